// Round 4
// baseline (683.741 us; speedup 1.0000x reference)
//
#include <hip/hip_runtime.h>
#include <hip/hip_bf16.h>
#include <math.h>

#define NUM_EMB 8192
#define DIM 512
#define NROWS 16384   // 32*512
#define NPART 4096    // gather_loss partial sums (one per block)

typedef unsigned short ushort;
typedef unsigned long long ull;
typedef __attribute__((ext_vector_type(8))) short short8;
typedef __attribute__((ext_vector_type(4))) float floatx4;
typedef __attribute__((ext_vector_type(16))) float floatx16;

// ---------------- helpers ----------------
__device__ __forceinline__ ushort f2bf(float f) {
    unsigned u = __float_as_uint(f);
    unsigned r = (u + 0x7fffu + ((u >> 16) & 1u)) >> 16;   // RNE
    return (ushort)r;
}
__device__ __forceinline__ float bf2f(ushort h) {
    return __uint_as_float(((unsigned)h) << 16);
}
__device__ __forceinline__ unsigned fmap(float f) {       // monotone float->uint
    unsigned u = __float_as_uint(f);
    return (u & 0x80000000u) ? ~u : (u | 0x80000000u);
}
__device__ __forceinline__ float funmap(unsigned m) {
    return __uint_as_float((m & 0x80000000u) ? (m ^ 0x80000000u) : ~m);
}
__device__ __forceinline__ void gld16(const void* g, void* l) {
    __builtin_amdgcn_global_load_lds(
        (const __attribute__((address_space(1))) void*)g,
        (__attribute__((address_space(3))) void*)l, 16, 0, 0);
}

// ---------- fused: fp32 -> bf16 hi/lo split + row sum of squares (+packed init) ----------
// one wave per row
__global__ __launch_bounds__(256) void split_rss_k(const float* __restrict__ src,
    ushort* __restrict__ hi, ushort* __restrict__ lo, float* __restrict__ ss,
    ull* __restrict__ packed, int nrows)
{
    int gid  = blockIdx.x * blockDim.x + threadIdx.x;
    int row  = gid >> 6;
    int lane = threadIdx.x & 63;
    if (row >= nrows) return;
    const float4* r = (const float4*)(src + (size_t)row * DIM);
    ushort4* h4 = (ushort4*)(hi + (size_t)row * DIM);
    ushort4* l4 = (ushort4*)(lo + (size_t)row * DIM);
    float s = 0.f;
#pragma unroll
    for (int i = lane; i < DIM / 4; i += 64) {
        float4 v = r[i];
        s += v.x * v.x + v.y * v.y + v.z * v.z + v.w * v.w;
        ushort4 h, l;
        h.x = f2bf(v.x); l.x = f2bf(v.x - bf2f(h.x));
        h.y = f2bf(v.y); l.y = f2bf(v.y - bf2f(h.y));
        h.z = f2bf(v.z); l.z = f2bf(v.z - bf2f(h.z));
        h.w = f2bf(v.w); l.w = f2bf(v.w - bf2f(h.w));
        h4[i] = h; l4[i] = l;
    }
#pragma unroll
    for (int off = 32; off > 0; off >>= 1) s += __shfl_down(s, off, 64);
    if (lane == 0) {
        ss[row] = s;
        if (packed) packed[row] = ~0ull;   // fused init (x-pass only)
    }
}

// ---------- MFMA distance + argmin ----------
// 256x256 tile, 512 threads (8 waves, 2x4), BK=32, double-buffered LDS (128 KiB).
// Same 4-phase counted-vmcnt schedule as round-3 (verified), but with
// v_mfma_f32_32x32x16_bf16: +15% pipe rate, HALF the MFMA instruction count
// (48 vs 96 per wave per K-tile) at identical ds_read bytes -> relieves the
// issue-slot crowding the round-3 counters showed (MfmaUtil 43 + VALUBusy 28).
// Fragment layout (standard CDNA 32x32 mapping, dual of the proven 16x16 one):
//   A: row = lane&31, k = (lane>>5)*8 + j ; B: col = lane&31, same k
//   C/D: col = lane&31, row = (reg&3) + 8*(reg>>2) + 4*(lane>>5)  [m74/m101]
// LDS cell swizzle unchanged: row r cell p holds global segment p ^ ((r>>1)&3);
// fragment read cell = ((s<<1)+(lane>>5)) ^ ((lane>>1)&3). 8 consecutive lanes
// touch 4 cells x 2 row-parities = all 32 banks -> conflict-free like current.
// XCD swizzle: 2048 blocks = 8 x 256 exactly; each XCD gets 4 consecutive
// B-panels (2 MB -> L2-resident) instead of thrashing all 16 MB.
__global__ __launch_bounds__(512, 2) void dist_mfma_k(
    const ushort* __restrict__ xh, const ushort* __restrict__ xl,
    const ushort* __restrict__ ch, const ushort* __restrict__ cl,
    const float* __restrict__ e2, ull* __restrict__ packed)
{
    __shared__ ushort Ah[2][256 * 32];
    __shared__ ushort Al[2][256 * 32];
    __shared__ ushort Bh[2][256 * 32];
    __shared__ ushort Bl[2][256 * 32];

    const int tid  = threadIdx.x;
    const int lane = tid & 63;
    const int w    = tid >> 6;
    const int wm   = w >> 2, wn = w & 3;   // 2x4 wave grid; per-wave tile 128x64

    // bijective XCD swizzle (2048 = 8*256)
    const int bid  = blockIdx.x + (blockIdx.y << 6);
    const int sid  = ((bid & 7) << 8) + (bid >> 3);
    const int row0 = (sid & 63) * 256;
    const int col0 = (sid >> 6) * 256;

    floatx16 acc[4][2];
#pragma unroll
    for (int m = 0; m < 4; ++m)
#pragma unroll
        for (int n = 0; n < 2; ++n)
#pragma unroll
            for (int r = 0; r < 16; ++r) acc[m][n][r] = 0.f;

    // staging coords: granule = one array's row-half h (identical to round-3).
    const int u = tid & 255, b = tid >> 8;
    const int p = u & 3;
    const int r_h0 = b * 128 + (u >> 2);     // rows for half 0 (0-63, 128-191)
    const int r_h1 = r_h0 + 64;              // rows for half 1 (64-127, 192-255)
    const int seg0 = (p ^ ((r_h0 >> 1) & 3)) * 8;
    const int seg1 = (p ^ ((r_h1 >> 1) & 3)) * 8;
    const int lo_h0 = (r_h0 * 4 + p) * 8;    // lds ushort offset within array
    const int lo_h1 = (r_h1 * 4 + p) * 8;
    const int gA0 = (row0 + r_h0) * DIM + seg0;   // + dk
    const int gA1 = (row0 + r_h1) * DIM + seg1;
    const int gB0 = (col0 + r_h0) * DIM + seg0;
    const int gB1 = (col0 + r_h1) * DIM + seg1;

    // fragment addressing: row = base + (lane&31); cell(s) = ((s<<1)+(lane>>5)) ^ ((lane>>1)&3)
    const int lr   = lane & 31;
    const int fc0  = (((lane >> 5)) ^ ((lane >> 1) & 3)) * 8;
    const int fc1  = ((2 + (lane >> 5)) ^ ((lane >> 1) & 3)) * 8;

    short8 ah[2][2], al[2][2], bh[2][2], bl[2][2];   // [mm|ni][s]

#define ISSUE_A(B_, h_, dk_) do { \
    if (h_) { gld16(&xh[gA1 + (dk_)], &Ah[B_][lo_h1]); gld16(&xl[gA1 + (dk_)], &Al[B_][lo_h1]); } \
    else    { gld16(&xh[gA0 + (dk_)], &Ah[B_][lo_h0]); gld16(&xl[gA0 + (dk_)], &Al[B_][lo_h0]); } } while (0)
#define ISSUE_B(B_, h_, dk_) do { \
    if (h_) { gld16(&ch[gB1 + (dk_)], &Bh[B_][lo_h1]); gld16(&cl[gB1 + (dk_)], &Bl[B_][lo_h1]); } \
    else    { gld16(&ch[gB0 + (dk_)], &Bh[B_][lo_h0]); gld16(&cl[gB0 + (dk_)], &Bl[B_][lo_h0]); } } while (0)
#define LOAD_A(B_, mh_) do { \
    _Pragma("unroll") for (int mm = 0; mm < 2; ++mm) \
    _Pragma("unroll") for (int s = 0; s < 2; ++s) { \
        const int o = (wm * 128 + ((mh_) * 2 + mm) * 32 + lr) * 32 + (s ? fc1 : fc0); \
        ah[mm][s] = *(const short8*)&Ah[B_][o]; \
        al[mm][s] = *(const short8*)&Al[B_][o]; } } while (0)
#define LOAD_B(B_, nh_) do { \
    _Pragma("unroll") for (int s = 0; s < 2; ++s) { \
        const int o = (wn * 64 + (nh_) * 32 + lr) * 32 + (s ? fc1 : fc0); \
        bh[nh_][s] = *(const short8*)&Bh[B_][o]; \
        bl[nh_][s] = *(const short8*)&Bl[B_][o]; } } while (0)
#define DO_MFMA(mh_, ni_) do { \
    __builtin_amdgcn_s_setprio(1); \
    _Pragma("unroll") for (int s = 0; s < 2; ++s) { \
        _Pragma("unroll") for (int mm = 0; mm < 2; ++mm) \
            acc[(mh_) * 2 + mm][ni_] = __builtin_amdgcn_mfma_f32_32x32x16_bf16(ah[mm][s], bh[ni_][s], acc[(mh_) * 2 + mm][ni_], 0, 0, 0); \
        _Pragma("unroll") for (int mm = 0; mm < 2; ++mm) \
            acc[(mh_) * 2 + mm][ni_] = __builtin_amdgcn_mfma_f32_32x32x16_bf16(ah[mm][s], bl[ni_][s], acc[(mh_) * 2 + mm][ni_], 0, 0, 0); \
        _Pragma("unroll") for (int mm = 0; mm < 2; ++mm) \
            acc[(mh_) * 2 + mm][ni_] = __builtin_amdgcn_mfma_f32_32x32x16_bf16(al[mm][s], bh[ni_][s], acc[(mh_) * 2 + mm][ni_], 0, 0, 0); \
    } \
    __builtin_amdgcn_s_setprio(0); } while (0)

    // prologue: stage all of tile 0 (issue-order = need-order), drain once
    ISSUE_A(0, 0, 0);
    ISSUE_B(0, 0, 0);
    ISSUE_B(0, 1, 0);
    ISSUE_A(0, 1, 0);
    asm volatile("s_waitcnt vmcnt(0)" ::: "memory");
    __builtin_amdgcn_s_barrier();
    __builtin_amdgcn_sched_barrier(0);

#pragma unroll 1
    for (int t = 0; t < 16; ++t) {
        const int B = t & 1, Bn = B ^ 1;
        const int dkn = (t + 1) * 32;
        const bool pf = (t < 15);

        // ---- phase 0: (mh0, n0); prefetch A-h0 of tile t+1 ----
        LOAD_A(B, 0);
        LOAD_B(B, 0);
        if (pf) ISSUE_A(Bn, 0, dkn);
        DO_MFMA(0, 0);
        if (pf) { asm volatile("s_waitcnt vmcnt(4)" ::: "memory"); }
        else    { asm volatile("s_waitcnt vmcnt(2)" ::: "memory"); }
        __builtin_amdgcn_s_barrier();
        __builtin_amdgcn_sched_barrier(0);

        // ---- phase 1: (mh0, n1); prefetch B-h0 ----
        LOAD_B(B, 1);
        if (pf) ISSUE_B(Bn, 0, dkn);
        DO_MFMA(0, 1);
        if (pf) { asm volatile("s_waitcnt vmcnt(4)" ::: "memory"); }
        else    { asm volatile("s_waitcnt vmcnt(0)" ::: "memory"); }
        __builtin_amdgcn_s_barrier();
        __builtin_amdgcn_sched_barrier(0);

        // ---- phase 2: (mh1, n1); prefetch B-h1 ----
        LOAD_A(B, 1);
        if (pf) ISSUE_B(Bn, 1, dkn);
        DO_MFMA(1, 1);
        __builtin_amdgcn_s_barrier();          // p3 reads no LDS: no wait here
        __builtin_amdgcn_sched_barrier(0);

        // ---- phase 3: (mh1, n0), all frags already in regs; prefetch A-h1 ----
        if (pf) ISSUE_A(Bn, 1, dkn);
        DO_MFMA(1, 0);
        if (pf) { asm volatile("s_waitcnt vmcnt(4)" ::: "memory"); }
        __builtin_amdgcn_s_barrier();
        __builtin_amdgcn_sched_barrier(0);
    }

#undef ISSUE_A
#undef ISSUE_B
#undef LOAD_A
#undef LOAD_B
#undef DO_MFMA

    // epilogue: v = e2[c] - 2*dot ; argmin with first-occurrence tie-break
    // C/D: col = ni*32 + (lane&31); row = mi*32 + (reg&3) + 8*(reg>>2) + 4*(lane>>5)
    float e2v[2];
    int   cidx[2];
    cidx[0] = col0 + wn * 64 + lr;
    cidx[1] = cidx[0] + 32;
    e2v[0]  = e2[cidx[0]];
    e2v[1]  = e2[cidx[1]];
    const int rbase = row0 + wm * 128 + ((lane >> 5) << 2);
#pragma unroll
    for (int mi = 0; mi < 4; ++mi) {
#pragma unroll
        for (int rg = 0; rg < 16; ++rg) {
            float v0 = e2v[0] - 2.f * acc[mi][0][rg];
            float v1 = e2v[1] - 2.f * acc[mi][1][rg];
            float bv; int bi;
            if (v1 < v0) { bv = v1; bi = cidx[1]; }
            else         { bv = v0; bi = cidx[0]; }   // ties -> smaller index
#pragma unroll
            for (int mk = 1; mk < 32; mk <<= 1) {     // 32-lane butterfly (stays in half)
                float ov = __shfl_xor(bv, mk, 64);
                int   oi = __shfl_xor(bi, mk, 64);
                if (ov < bv || (ov == bv && oi < bi)) { bv = ov; bi = oi; }
            }
            if ((lane & 31) == 0) {
                int grow = rbase + mi * 32 + (rg & 3) + ((rg >> 2) << 3);
                ull pack = ((ull)fmap(bv) << 32) | (unsigned)bi;
                atomicMin(&packed[grow], pack);
            }
        }
    }
}

// ---------- fused merge + gather + loss partials ----------
// unpack argmin, write indices/min_dist, gather codebook row, partial sum (x-q)^2
__global__ __launch_bounds__(256) void gather_loss_k(const float* __restrict__ x,
    const float* __restrict__ cb, const ull* __restrict__ packed,
    const float* __restrict__ x2, float* __restrict__ outq,
    float* __restrict__ out_idx, float* __restrict__ out_mind,
    float* __restrict__ partials)
{
    __shared__ float ps[4];
    int gid  = blockIdx.x * blockDim.x + threadIdx.x;
    int row  = gid >> 6;
    int lane = threadIdx.x & 63;
    int w    = threadIdx.x >> 6;
    float s = 0.f;
    if (row < NROWS) {
        ull p = packed[row];                 // same-address within wave: broadcast
        int k = (int)(p & 0xffffffffull);
        if (lane == 0) {
            out_idx[row]  = (float)k;
            out_mind[row] = x2[row] + funmap((unsigned)(p >> 32));
        }
        const float4* q  = (const float4*)(cb + (size_t)k * DIM);
        const float4* xr = (const float4*)(x + (size_t)row * DIM);
        float4* o = (float4*)(outq + (size_t)row * DIM);
#pragma unroll
        for (int i = lane; i < DIM / 4; i += 64) {
            float4 qv = q[i], xv = xr[i];
            o[i] = qv;
            float dx = xv.x - qv.x, dy = xv.y - qv.y;
            float dz = xv.z - qv.z, dw = xv.w - qv.w;
            s += dx * dx + dy * dy + dz * dz + dw * dw;
        }
    }
#pragma unroll
    for (int off = 32; off > 0; off >>= 1) s += __shfl_down(s, off, 64);
    if (lane == 0) ps[w] = s;
    __syncthreads();
    if (threadIdx.x == 0) partials[blockIdx.x] = ps[0] + ps[1] + ps[2] + ps[3];
}

// ---------- final reduction of partials -> loss outputs ----------
__global__ __launch_bounds__(256) void finalize_k(const float* __restrict__ partials,
    float* __restrict__ out_loss, float* __restrict__ out_commit)
{
    __shared__ float ps[4];
    int t = threadIdx.x, lane = t & 63, w = t >> 6;
    float s = 0.f;
#pragma unroll
    for (int i = 0; i < NPART / 256; ++i) s += partials[t + 256 * i];
#pragma unroll
    for (int off = 32; off > 0; off >>= 1) s += __shfl_down(s, off, 64);
    if (lane == 0) ps[w] = s;
    __syncthreads();
    if (t == 0) {
        float tot = ps[0] + ps[1] + ps[2] + ps[3];
        *out_loss   = 0.25f * tot + tot;
        *out_commit = tot;
    }
}

// ================= fallback (fp32 path, small ws) =================
#define BM 64
#define BN 64
#define BK 32
#define KSPLIT 4
#define KPER (NUM_EMB / KSPLIT)
#define NCT (KPER / BN)

__global__ __launch_bounds__(256) void rowsumsq_k(const float* __restrict__ a,
                                                  float* __restrict__ out, int nrows)
{
    int gid  = blockIdx.x * blockDim.x + threadIdx.x;
    int row  = gid >> 6;
    int lane = threadIdx.x & 63;
    if (row >= nrows) return;
    const float4* r = (const float4*)(a + (size_t)row * DIM);
    float s = 0.f;
#pragma unroll
    for (int i = lane; i < DIM / 4; i += 64) {
        float4 v = r[i];
        s += v.x * v.x + v.y * v.y + v.z * v.z + v.w * v.w;
    }
#pragma unroll
    for (int off = 32; off > 0; off >>= 1) s += __shfl_down(s, off, 64);
    if (lane == 0) out[row] = s;
}

__global__ __launch_bounds__(256) void dist_argmin_old_k(const float* __restrict__ x,
    const float* __restrict__ cb, const float* __restrict__ e2,
    float* __restrict__ part_m, int* __restrict__ part_i)
{
    __shared__ __align__(16) float As[BK][BM + 4];
    __shared__ __align__(16) float Bs[BK][BN + 4];
    __shared__ float redv[BM][16];
    __shared__ int   redi[BM][16];

    const int row0 = blockIdx.x * BM;
    const int ks   = blockIdx.y;
    const int cbeg = ks * KPER;
    const int t    = threadIdx.x;
    const int tx   = t & 15;
    const int ty   = t >> 4;
    const int ld_d = t & 31;
    const int ld_r = t >> 5;

    float minm[4]; int mini[4];
#pragma unroll
    for (int i = 0; i < 4; ++i) { minm[i] = INFINITY; mini[i] = 0; }

    for (int ct = 0; ct < NCT; ++ct) {
        const int c0 = cbeg + ct * BN;
        float acc[4][4];
#pragma unroll
        for (int i = 0; i < 4; ++i)
#pragma unroll
            for (int j = 0; j < 4; ++j) acc[i][j] = 0.f;
        for (int dc = 0; dc < DIM; dc += BK) {
#pragma unroll
            for (int rr = 0; rr < BM; rr += 8)
                As[ld_d][ld_r + rr] = x[(size_t)(row0 + ld_r + rr) * DIM + dc + ld_d];
#pragma unroll
            for (int rr = 0; rr < BN; rr += 8)
                Bs[ld_d][ld_r + rr] = cb[(size_t)(c0 + ld_r + rr) * DIM + dc + ld_d];
            __syncthreads();
#pragma unroll
            for (int d = 0; d < BK; ++d) {
                float4 av = *(const float4*)&As[d][4 * ty];
                float4 bv = *(const float4*)&Bs[d][4 * tx];
                acc[0][0] += av.x * bv.x; acc[0][1] += av.x * bv.y;
                acc[0][2] += av.x * bv.z; acc[0][3] += av.x * bv.w;
                acc[1][0] += av.y * bv.x; acc[1][1] += av.y * bv.y;
                acc[1][2] += av.y * bv.z; acc[1][3] += av.y * bv.w;
                acc[2][0] += av.z * bv.x; acc[2][1] += av.z * bv.y;
                acc[2][2] += av.z * bv.z; acc[2][3] += av.z * bv.w;
                acc[3][0] += av.w * bv.x; acc[3][1] += av.w * bv.y;
                acc[3][2] += av.w * bv.z; acc[3][3] += av.w * bv.w;
            }
            __syncthreads();
        }
#pragma unroll
        for (int j = 0; j < 4; ++j) {
            const int c = c0 + 4 * tx + j;
            const float e = e2[c];
#pragma unroll
            for (int i = 0; i < 4; ++i) {
                float m = e - 2.f * acc[i][j];
                if (m < minm[i]) { minm[i] = m; mini[i] = c; }
            }
        }
    }
#pragma unroll
    for (int i = 0; i < 4; ++i) {
        redv[4 * ty + i][tx] = minm[i];
        redi[4 * ty + i][tx] = mini[i];
    }
    __syncthreads();
    if (t < BM) {
        float bm = INFINITY; int bi = 0;
#pragma unroll
        for (int c = 0; c < 16; ++c) {
            float v = redv[t][c];
            if (v < bm) { bm = v; bi = redi[t][c]; }
        }
        part_m[(size_t)(row0 + t) * KSPLIT + ks] = bm;
        part_i[(size_t)(row0 + t) * KSPLIT + ks] = bi;
    }
}

__global__ __launch_bounds__(256) void merge_pack_k(const float* __restrict__ part_m,
    const int* __restrict__ part_i, ull* __restrict__ packed)
{
    int row = blockIdx.x * blockDim.x + threadIdx.x;
    if (row >= NROWS) return;
    float bm = INFINITY; int bi = 0;
#pragma unroll
    for (int s = 0; s < KSPLIT; ++s) {
        float v = part_m[(size_t)row * KSPLIT + s];
        if (v < bm) { bm = v; bi = part_i[(size_t)row * KSPLIT + s]; }
    }
    packed[row] = ((ull)fmap(bm) << 32) | (unsigned)bi;
}

// ================= launch =================
extern "C" void kernel_launch(void* const* d_in, const int* in_sizes, int n_in,
                              void* d_out, int out_size, void* d_ws, size_t ws_size,
                              hipStream_t stream)
{
    const float* x  = (const float*)d_in[0];   // [16384, 512]
    const float* cb = (const float*)d_in[1];   // [8192, 512]
    float* out = (float*)d_out;

    float* outq       = out;
    float* out_loss   = out + 8388608;
    float* out_idx    = out + 8388609;
    float* out_mind   = out + 8388609 + 16384;
    float* out_commit = out + 8388609 + 2 * 16384;

    char* ws = (char*)d_ws;
    float* e2      = (float*)ws;   ws += NUM_EMB * 4;
    float* x2      = (float*)ws;   ws += NROWS * 4;
    ull*   packed  = (ull*)ws;     ws += NROWS * 8;
    float* partials= (float*)ws;   ws += NPART * 4;
    ushort* xh = (ushort*)ws;      ws += (size_t)NROWS * DIM * 2;
    ushort* xl = (ushort*)ws;      ws += (size_t)NROWS * DIM * 2;
    ushort* ch = (ushort*)ws;      ws += (size_t)NUM_EMB * DIM * 2;
    ushort* cl = (ushort*)ws;      ws += (size_t)NUM_EMB * DIM * 2;
    size_t need_fast = (size_t)(ws - (char*)d_ws);

    if (ws_size >= need_fast) {
        split_rss_k<<<NROWS / 4, 256, 0, stream>>>(x, xh, xl, x2, packed, NROWS);
        split_rss_k<<<NUM_EMB / 4, 256, 0, stream>>>(cb, ch, cl, e2, (ull*)0, NUM_EMB);
        dim3 grid(NROWS / 256, NUM_EMB / 256);
        dist_mfma_k<<<grid, 512, 0, stream>>>(xh, xl, ch, cl, e2, packed);
    } else {
        // fallback: fp32 path (small ws)
        rowsumsq_k<<<NUM_EMB / 4, 256, 0, stream>>>(cb, e2, NUM_EMB);
        rowsumsq_k<<<NROWS / 4, 256, 0, stream>>>(x, x2, NROWS);
        float* pm = (float*)((char*)d_ws + NUM_EMB * 4 + NROWS * 4 + NROWS * 8 + NPART * 4);
        int*   pi = (int*)(pm + (size_t)NROWS * KSPLIT);
        dim3 grid(NROWS / BM, KSPLIT);
        dist_argmin_old_k<<<grid, 256, 0, stream>>>(x, cb, e2, pm, pi);
        merge_pack_k<<<NROWS / 256, 256, 0, stream>>>(pm, pi, packed);
    }

    gather_loss_k<<<NROWS / 4, 256, 0, stream>>>(x, cb, packed, x2, outq,
                                                 out_idx, out_mind, partials);
    finalize_k<<<1, 256, 0, stream>>>(partials, out_loss, out_commit);
}

// Round 5
// 512.206 us; speedup vs baseline: 1.3349x; 1.3349x over previous
//
#include <hip/hip_runtime.h>
#include <hip/hip_bf16.h>
#include <math.h>

#define NUM_EMB 8192
#define DIM 512
#define NROWS 16384   // 32*512
#define NPART 4096    // gather_loss partial sums (one per block)

typedef unsigned short ushort;
typedef unsigned long long ull;
typedef __attribute__((ext_vector_type(8))) short short8;
typedef __attribute__((ext_vector_type(4))) float floatx4;

// ---------------- helpers ----------------
__device__ __forceinline__ ushort f2bf(float f) {
    unsigned u = __float_as_uint(f);
    unsigned r = (u + 0x7fffu + ((u >> 16) & 1u)) >> 16;   // RNE
    return (ushort)r;
}
__device__ __forceinline__ float bf2f(ushort h) {
    return __uint_as_float(((unsigned)h) << 16);
}
__device__ __forceinline__ unsigned fmap(float f) {       // monotone float->uint
    unsigned u = __float_as_uint(f);
    return (u & 0x80000000u) ? ~u : (u | 0x80000000u);
}
__device__ __forceinline__ float funmap(unsigned m) {
    return __uint_as_float((m & 0x80000000u) ? (m ^ 0x80000000u) : ~m);
}
__device__ __forceinline__ void gld16(const void* g, void* l) {
    __builtin_amdgcn_global_load_lds(
        (const __attribute__((address_space(1))) void*)g,
        (__attribute__((address_space(3))) void*)l, 16, 0, 0);
}

// ---------- fused: fp32 -> bf16 hi/lo split + row sum of squares (+packed init) ----------
// one wave per row
__global__ __launch_bounds__(256) void split_rss_k(const float* __restrict__ src,
    ushort* __restrict__ hi, ushort* __restrict__ lo, float* __restrict__ ss,
    ull* __restrict__ packed, int nrows)
{
    int gid  = blockIdx.x * blockDim.x + threadIdx.x;
    int row  = gid >> 6;
    int lane = threadIdx.x & 63;
    if (row >= nrows) return;
    const float4* r = (const float4*)(src + (size_t)row * DIM);
    ushort4* h4 = (ushort4*)(hi + (size_t)row * DIM);
    ushort4* l4 = (ushort4*)(lo + (size_t)row * DIM);
    float s = 0.f;
#pragma unroll
    for (int i = lane; i < DIM / 4; i += 64) {
        float4 v = r[i];
        s += v.x * v.x + v.y * v.y + v.z * v.z + v.w * v.w;
        ushort4 h, l;
        h.x = f2bf(v.x); l.x = f2bf(v.x - bf2f(h.x));
        h.y = f2bf(v.y); l.y = f2bf(v.y - bf2f(h.y));
        h.z = f2bf(v.z); l.z = f2bf(v.z - bf2f(h.z));
        h.w = f2bf(v.w); l.w = f2bf(v.w - bf2f(h.w));
        h4[i] = h; l4[i] = l;
    }
#pragma unroll
    for (int off = 32; off > 0; off >>= 1) s += __shfl_down(s, off, 64);
    if (lane == 0) {
        ss[row] = s;
        if (packed) packed[row] = ~0ull;   // fused init (x-pass only)
    }
}

// ---------- MFMA distance + argmin ----------
// 256x256 tile, 512 threads (8 waves, 2x4), BK=32, double-buffered LDS (128 KiB).
// Round-3 structure (16x16x32, verified) with two fixes:
//  (1) RACE FIX: B staging granules are bit5-interleaved (h0 = rows with
//      (row&32)==0), matching LOAD_B's read set (rows wn*64+nh*32+0..31 have
//      bit5==nh for ALL waves). A granules stay bit6-split (LOAD_A reads
//      wm*128+mh*64+0..63, bit6==mh). With this the vmcnt ledger is exact:
//      issue p0:A-h0, p1:B-h0, p2:B-h1, p3:A-h1 (all for tile t+1);
//      end p0 vmcnt(4) publishes B-h1(t)   [needed p1, issued t-1 p2]
//      end p1 vmcnt(4) publishes A-h1(t)   [needed p2, issued t-1 p3]
//      end p3 vmcnt(4) publishes A-h0,B-h0(t+1) [needed next p0]
//      every drained load >= 2 phases (~1500 cyc) old.
//  (2) m201 phase shape: {ds_read + gld16 issue, sched_barrier, s_barrier,
//      MFMA (setprio), counted vmcnt, s_barrier}. The barrier between
//      ds_read-issue and MFMA lets read latency hide under convergence and
//      the co-resident wave's MFMA (m196: this interleave is the lever).
// LDS cell swizzle unchanged (0 conflicts measured): row r cell q holds
// global segment q ^ ((r>>1)&3); fragment reads use the matching XOR.
__global__ __launch_bounds__(512, 2) void dist_mfma_k(
    const ushort* __restrict__ xh, const ushort* __restrict__ xl,
    const ushort* __restrict__ ch, const ushort* __restrict__ cl,
    const float* __restrict__ e2, ull* __restrict__ packed)
{
    __shared__ ushort Ah[2][256 * 32];
    __shared__ ushort Al[2][256 * 32];
    __shared__ ushort Bh[2][256 * 32];
    __shared__ ushort Bl[2][256 * 32];

    const int tid  = threadIdx.x;
    const int lane = tid & 63;
    const int w    = tid >> 6;
    const int wm   = w >> 2, wn = w & 3;   // 2x4 wave grid; per-wave tile 128x64
    const int row0 = blockIdx.x * 256;
    const int col0 = blockIdx.y * 256;

    floatx4 acc[8][4];
#pragma unroll
    for (int m = 0; m < 8; ++m)
#pragma unroll
        for (int n = 0; n < 4; ++n) acc[m][n] = (floatx4){0.f, 0.f, 0.f, 0.f};

    // staging coords: granule = one array's row-half h, 8 KiB = 1 gld16/thread.
    const int u = tid & 255, b = tid >> 8;
    const int p = u & 3;
    // A granules: bit6-split (rows b*128 + h*64 + 0..63)
    const int rA0 = b * 128 + (u >> 2);
    const int rA1 = rA0 + 64;
    const int sA0 = (p ^ ((rA0 >> 1) & 3)) * 8;
    const int sA1 = (p ^ ((rA1 >> 1) & 3)) * 8;
    const int loA0 = (rA0 * 4 + p) * 8;      // lds ushort offset within array
    const int loA1 = (rA1 * 4 + p) * 8;
    const int gA0 = (row0 + rA0) * DIM + sA0;   // + dk
    const int gA1 = (row0 + rA1) * DIM + sA1;
    // B granules: bit5-interleaved (h0 = rows with bit5==0)
    const int vB  = u >> 2;
    const int rB0 = b * 128 + (vB & 31) + ((vB & 32) << 1);
    const int rB1 = rB0 + 32;
    const int sB0 = (p ^ ((rB0 >> 1) & 3)) * 8;
    const int sB1 = (p ^ ((rB1 >> 1) & 3)) * 8;
    const int loB0 = (rB0 * 4 + p) * 8;
    const int loB1 = (rB1 * 4 + p) * 8;
    const int gB0 = (col0 + rB0) * DIM + sB0;
    const int gB1 = (col0 + rB1) * DIM + sB1;

    // fragment base: row (lane&15), cell (lane>>4) ^ ((lane>>1)&3)
    const int fr = (lane & 15) * 32 + (((lane >> 4) ^ ((lane >> 1) & 3)) * 8);

    short8 ah[4], al[4], bh[4], bl[4];

#define ISSUE_A(B_, h_, dk_) do { \
    if (h_) { gld16(&xh[gA1 + (dk_)], &Ah[B_][loA1]); gld16(&xl[gA1 + (dk_)], &Al[B_][loA1]); } \
    else    { gld16(&xh[gA0 + (dk_)], &Ah[B_][loA0]); gld16(&xl[gA0 + (dk_)], &Al[B_][loA0]); } } while (0)
#define ISSUE_B(B_, h_, dk_) do { \
    if (h_) { gld16(&ch[gB1 + (dk_)], &Bh[B_][loB1]); gld16(&cl[gB1 + (dk_)], &Bl[B_][loB1]); } \
    else    { gld16(&ch[gB0 + (dk_)], &Bh[B_][loB0]); gld16(&cl[gB0 + (dk_)], &Bl[B_][loB0]); } } while (0)
#define LOAD_A(B_, mh_) do { \
    _Pragma("unroll") for (int m = 0; m < 4; ++m) { \
        const int o = (wm * 128 + (mh_) * 64 + m * 16) * 32 + fr; \
        ah[m] = *(const short8*)&Ah[B_][o]; \
        al[m] = *(const short8*)&Al[B_][o]; } } while (0)
#define LOAD_B(B_, nh_) do { \
    _Pragma("unroll") for (int n = 0; n < 2; ++n) { \
        const int o = (wn * 64 + (nh_) * 32 + n * 16) * 32 + fr; \
        bh[(nh_) * 2 + n] = *(const short8*)&Bh[B_][o]; \
        bl[(nh_) * 2 + n] = *(const short8*)&Bl[B_][o]; } } while (0)
#define DO_MFMA(mh_, nh_) do { \
    __builtin_amdgcn_s_setprio(1); \
    _Pragma("unroll") for (int m = 0; m < 4; ++m) \
    _Pragma("unroll") for (int n = 0; n < 2; ++n) { \
        acc[(mh_) * 4 + m][(nh_) * 2 + n] = __builtin_amdgcn_mfma_f32_16x16x32_bf16(ah[m], bh[(nh_) * 2 + n], acc[(mh_) * 4 + m][(nh_) * 2 + n], 0, 0, 0); \
        acc[(mh_) * 4 + m][(nh_) * 2 + n] = __builtin_amdgcn_mfma_f32_16x16x32_bf16(ah[m], bl[(nh_) * 2 + n], acc[(mh_) * 4 + m][(nh_) * 2 + n], 0, 0, 0); \
        acc[(mh_) * 4 + m][(nh_) * 2 + n] = __builtin_amdgcn_mfma_f32_16x16x32_bf16(al[m], bh[(nh_) * 2 + n], acc[(mh_) * 4 + m][(nh_) * 2 + n], 0, 0, 0); \
    } \
    __builtin_amdgcn_s_setprio(0); } while (0)
#define MIDBAR() do { \
    __builtin_amdgcn_sched_barrier(0); \
    __builtin_amdgcn_s_barrier(); \
    __builtin_amdgcn_sched_barrier(0); } while (0)
#define ENDBAR() do { \
    __builtin_amdgcn_s_barrier(); \
    __builtin_amdgcn_sched_barrier(0); } while (0)

    // prologue: stage all of tile 0 (issue-order = need-order), drain once
    ISSUE_A(0, 0, 0);
    ISSUE_B(0, 0, 0);
    ISSUE_B(0, 1, 0);
    ISSUE_A(0, 1, 0);
    asm volatile("s_waitcnt vmcnt(0)" ::: "memory");
    __builtin_amdgcn_s_barrier();
    __builtin_amdgcn_sched_barrier(0);

#pragma unroll 1
    for (int t = 0; t < 16; ++t) {
        const int B = t & 1, Bn = B ^ 1;
        const int dkn = (t + 1) * 32;
        const bool pf = (t < 15);

        // ---- phase 0: quadrant (0,0); prefetch A-h0 of tile t+1 ----
        LOAD_A(B, 0);
        LOAD_B(B, 0);
        if (pf) ISSUE_A(Bn, 0, dkn);
        MIDBAR();                              // ds_reads fly during convergence
        DO_MFMA(0, 0);
        if (pf) { asm volatile("s_waitcnt vmcnt(4)" ::: "memory"); }
        else    { asm volatile("s_waitcnt vmcnt(2)" ::: "memory"); }
        ENDBAR();                              // publishes B-h1(t)

        // ---- phase 1: quadrant (0,1); prefetch B-h0 ----
        LOAD_B(B, 1);
        if (pf) ISSUE_B(Bn, 0, dkn);
        MIDBAR();
        DO_MFMA(0, 1);
        if (pf) { asm volatile("s_waitcnt vmcnt(4)" ::: "memory"); }
        else    { asm volatile("s_waitcnt vmcnt(0)" ::: "memory"); }
        ENDBAR();                              // publishes A-h1(t)

        // ---- phase 2: quadrant (1,1); prefetch B-h1 ----
        LOAD_A(B, 1);
        if (pf) ISSUE_B(Bn, 1, dkn);
        MIDBAR();
        DO_MFMA(1, 1);
        ENDBAR();                              // p3 reads regs only: no wait

        // ---- phase 3: quadrant (1,0), all frags in regs; prefetch A-h1 ----
        if (pf) ISSUE_A(Bn, 1, dkn);
        MIDBAR();
        DO_MFMA(1, 0);
        if (pf) { asm volatile("s_waitcnt vmcnt(4)" ::: "memory"); }
        ENDBAR();                              // publishes A-h0,B-h0(t+1)
    }

#undef ISSUE_A
#undef ISSUE_B
#undef LOAD_A
#undef LOAD_B
#undef DO_MFMA
#undef MIDBAR
#undef ENDBAR

    // epilogue: v = e2[c] - 2*dot ; argmin with first-occurrence tie-break
    float e2v[4];
    int   cidx[4];
#pragma unroll
    for (int n = 0; n < 4; ++n) {
        cidx[n] = col0 + wn * 64 + n * 16 + (lane & 15);
        e2v[n]  = e2[cidx[n]];
    }
#pragma unroll
    for (int m = 0; m < 8; ++m) {
#pragma unroll
        for (int r = 0; r < 4; ++r) {
            float bv = INFINITY; int bi = 0x7fffffff;
#pragma unroll
            for (int n = 0; n < 4; ++n) {        // ascending code order
                float v = e2v[n] - 2.f * acc[m][n][r];
                if (v < bv) { bv = v; bi = cidx[n]; }
            }
#pragma unroll
            for (int mk = 1; mk < 16; mk <<= 1) {  // 16-lane butterfly (same quad group)
                float ov = __shfl_xor(bv, mk, 64);
                int   oi = __shfl_xor(bi, mk, 64);
                if (ov < bv || (ov == bv && oi < bi)) { bv = ov; bi = oi; }
            }
            if ((lane & 15) == 0) {
                int grow = row0 + wm * 128 + m * 16 + (lane >> 4) * 4 + r;
                ull pack = ((ull)fmap(bv) << 32) | (unsigned)bi;
                atomicMin(&packed[grow], pack);
            }
        }
    }
}

// ---------- fused merge + gather + loss partials ----------
// unpack argmin, write indices/min_dist, gather codebook row, partial sum (x-q)^2
__global__ __launch_bounds__(256) void gather_loss_k(const float* __restrict__ x,
    const float* __restrict__ cb, const ull* __restrict__ packed,
    const float* __restrict__ x2, float* __restrict__ outq,
    float* __restrict__ out_idx, float* __restrict__ out_mind,
    float* __restrict__ partials)
{
    __shared__ float ps[4];
    int gid  = blockIdx.x * blockDim.x + threadIdx.x;
    int row  = gid >> 6;
    int lane = threadIdx.x & 63;
    int w    = threadIdx.x >> 6;
    float s = 0.f;
    if (row < NROWS) {
        ull p = packed[row];                 // same-address within wave: broadcast
        int k = (int)(p & 0xffffffffull);
        if (lane == 0) {
            out_idx[row]  = (float)k;
            out_mind[row] = x2[row] + funmap((unsigned)(p >> 32));
        }
        const float4* q  = (const float4*)(cb + (size_t)k * DIM);
        const float4* xr = (const float4*)(x + (size_t)row * DIM);
        float4* o = (float4*)(outq + (size_t)row * DIM);
#pragma unroll
        for (int i = lane; i < DIM / 4; i += 64) {
            float4 qv = q[i], xv = xr[i];
            o[i] = qv;
            float dx = xv.x - qv.x, dy = xv.y - qv.y;
            float dz = xv.z - qv.z, dw = xv.w - qv.w;
            s += dx * dx + dy * dy + dz * dz + dw * dw;
        }
    }
#pragma unroll
    for (int off = 32; off > 0; off >>= 1) s += __shfl_down(s, off, 64);
    if (lane == 0) ps[w] = s;
    __syncthreads();
    if (threadIdx.x == 0) partials[blockIdx.x] = ps[0] + ps[1] + ps[2] + ps[3];
}

// ---------- final reduction of partials -> loss outputs ----------
__global__ __launch_bounds__(256) void finalize_k(const float* __restrict__ partials,
    float* __restrict__ out_loss, float* __restrict__ out_commit)
{
    __shared__ float ps[4];
    int t = threadIdx.x, lane = t & 63, w = t >> 6;
    float s = 0.f;
#pragma unroll
    for (int i = 0; i < NPART / 256; ++i) s += partials[t + 256 * i];
#pragma unroll
    for (int off = 32; off > 0; off >>= 1) s += __shfl_down(s, off, 64);
    if (lane == 0) ps[w] = s;
    __syncthreads();
    if (t == 0) {
        float tot = ps[0] + ps[1] + ps[2] + ps[3];
        *out_loss   = 0.25f * tot + tot;
        *out_commit = tot;
    }
}

// ================= fallback (fp32 path, small ws) =================
#define BM 64
#define BN 64
#define BK 32
#define KSPLIT 4
#define KPER (NUM_EMB / KSPLIT)
#define NCT (KPER / BN)

__global__ __launch_bounds__(256) void rowsumsq_k(const float* __restrict__ a,
                                                  float* __restrict__ out, int nrows)
{
    int gid  = blockIdx.x * blockDim.x + threadIdx.x;
    int row  = gid >> 6;
    int lane = threadIdx.x & 63;
    if (row >= nrows) return;
    const float4* r = (const float4*)(a + (size_t)row * DIM);
    float s = 0.f;
#pragma unroll
    for (int i = lane; i < DIM / 4; i += 64) {
        float4 v = r[i];
        s += v.x * v.x + v.y * v.y + v.z * v.z + v.w * v.w;
    }
#pragma unroll
    for (int off = 32; off > 0; off >>= 1) s += __shfl_down(s, off, 64);
    if (lane == 0) out[row] = s;
}

__global__ __launch_bounds__(256) void dist_argmin_old_k(const float* __restrict__ x,
    const float* __restrict__ cb, const float* __restrict__ e2,
    float* __restrict__ part_m, int* __restrict__ part_i)
{
    __shared__ __align__(16) float As[BK][BM + 4];
    __shared__ __align__(16) float Bs[BK][BN + 4];
    __shared__ float redv[BM][16];
    __shared__ int   redi[BM][16];

    const int row0 = blockIdx.x * BM;
    const int ks   = blockIdx.y;
    const int cbeg = ks * KPER;
    const int t    = threadIdx.x;
    const int tx   = t & 15;
    const int ty   = t >> 4;
    const int ld_d = t & 31;
    const int ld_r = t >> 5;

    float minm[4]; int mini[4];
#pragma unroll
    for (int i = 0; i < 4; ++i) { minm[i] = INFINITY; mini[i] = 0; }

    for (int ct = 0; ct < NCT; ++ct) {
        const int c0 = cbeg + ct * BN;
        float acc[4][4];
#pragma unroll
        for (int i = 0; i < 4; ++i)
#pragma unroll
            for (int j = 0; j < 4; ++j) acc[i][j] = 0.f;
        for (int dc = 0; dc < DIM; dc += BK) {
#pragma unroll
            for (int rr = 0; rr < BM; rr += 8)
                As[ld_d][ld_r + rr] = x[(size_t)(row0 + ld_r + rr) * DIM + dc + ld_d];
#pragma unroll
            for (int rr = 0; rr < BN; rr += 8)
                Bs[ld_d][ld_r + rr] = cb[(size_t)(c0 + ld_r + rr) * DIM + dc + ld_d];
            __syncthreads();
#pragma unroll
            for (int d = 0; d < BK; ++d) {
                float4 av = *(const float4*)&As[d][4 * ty];
                float4 bv = *(const float4*)&Bs[d][4 * tx];
                acc[0][0] += av.x * bv.x; acc[0][1] += av.x * bv.y;
                acc[0][2] += av.x * bv.z; acc[0][3] += av.x * bv.w;
                acc[1][0] += av.y * bv.x; acc[1][1] += av.y * bv.y;
                acc[1][2] += av.y * bv.z; acc[1][3] += av.y * bv.w;
                acc[2][0] += av.z * bv.x; acc[2][1] += av.z * bv.y;
                acc[2][2] += av.z * bv.z; acc[2][3] += av.z * bv.w;
                acc[3][0] += av.w * bv.x; acc[3][1] += av.w * bv.y;
                acc[3][2] += av.w * bv.z; acc[3][3] += av.w * bv.w;
            }
            __syncthreads();
        }
#pragma unroll
        for (int j = 0; j < 4; ++j) {
            const int c = c0 + 4 * tx + j;
            const float e = e2[c];
#pragma unroll
            for (int i = 0; i < 4; ++i) {
                float m = e - 2.f * acc[i][j];
                if (m < minm[i]) { minm[i] = m; mini[i] = c; }
            }
        }
    }
#pragma unroll
    for (int i = 0; i < 4; ++i) {
        redv[4 * ty + i][tx] = minm[i];
        redi[4 * ty + i][tx] = mini[i];
    }
    __syncthreads();
    if (t < BM) {
        float bm = INFINITY; int bi = 0;
#pragma unroll
        for (int c = 0; c < 16; ++c) {
            float v = redv[t][c];
            if (v < bm) { bm = v; bi = redi[t][c]; }
        }
        part_m[(size_t)(row0 + t) * KSPLIT + ks] = bm;
        part_i[(size_t)(row0 + t) * KSPLIT + ks] = bi;
    }
}

__global__ __launch_bounds__(256) void merge_pack_k(const float* __restrict__ part_m,
    const int* __restrict__ part_i, ull* __restrict__ packed)
{
    int row = blockIdx.x * blockDim.x + threadIdx.x;
    if (row >= NROWS) return;
    float bm = INFINITY; int bi = 0;
#pragma unroll
    for (int s = 0; s < KSPLIT; ++s) {
        float v = part_m[(size_t)row * KSPLIT + s];
        if (v < bm) { bm = v; bi = part_i[(size_t)row * KSPLIT + s]; }
    }
    packed[row] = ((ull)fmap(bm) << 32) | (unsigned)bi;
}

// ================= launch =================
extern "C" void kernel_launch(void* const* d_in, const int* in_sizes, int n_in,
                              void* d_out, int out_size, void* d_ws, size_t ws_size,
                              hipStream_t stream)
{
    const float* x  = (const float*)d_in[0];   // [16384, 512]
    const float* cb = (const float*)d_in[1];   // [8192, 512]
    float* out = (float*)d_out;

    float* outq       = out;
    float* out_loss   = out + 8388608;
    float* out_idx    = out + 8388609;
    float* out_mind   = out + 8388609 + 16384;
    float* out_commit = out + 8388609 + 2 * 16384;

    char* ws = (char*)d_ws;
    float* e2      = (float*)ws;   ws += NUM_EMB * 4;
    float* x2      = (float*)ws;   ws += NROWS * 4;
    ull*   packed  = (ull*)ws;     ws += NROWS * 8;
    float* partials= (float*)ws;   ws += NPART * 4;
    ushort* xh = (ushort*)ws;      ws += (size_t)NROWS * DIM * 2;
    ushort* xl = (ushort*)ws;      ws += (size_t)NROWS * DIM * 2;
    ushort* ch = (ushort*)ws;      ws += (size_t)NUM_EMB * DIM * 2;
    ushort* cl = (ushort*)ws;      ws += (size_t)NUM_EMB * DIM * 2;
    size_t need_fast = (size_t)(ws - (char*)d_ws);

    if (ws_size >= need_fast) {
        split_rss_k<<<NROWS / 4, 256, 0, stream>>>(x, xh, xl, x2, packed, NROWS);
        split_rss_k<<<NUM_EMB / 4, 256, 0, stream>>>(cb, ch, cl, e2, (ull*)0, NUM_EMB);
        dim3 grid(NROWS / 256, NUM_EMB / 256);
        dist_mfma_k<<<grid, 512, 0, stream>>>(xh, xl, ch, cl, e2, packed);
    } else {
        // fallback: fp32 path (small ws)
        rowsumsq_k<<<NUM_EMB / 4, 256, 0, stream>>>(cb, e2, NUM_EMB);
        rowsumsq_k<<<NROWS / 4, 256, 0, stream>>>(x, x2, NROWS);
        float* pm = (float*)((char*)d_ws + NUM_EMB * 4 + NROWS * 4 + NROWS * 8 + NPART * 4);
        int*   pi = (int*)(pm + (size_t)NROWS * KSPLIT);
        dim3 grid(NROWS / BM, KSPLIT);
        dist_argmin_old_k<<<grid, 256, 0, stream>>>(x, cb, e2, pm, pi);
        merge_pack_k<<<NROWS / 256, 256, 0, stream>>>(pm, pi, packed);
    }

    gather_loss_k<<<NROWS / 4, 256, 0, stream>>>(x, cb, packed, x2, outq,
                                                 out_idx, out_mind, partials);
    finalize_k<<<1, 256, 0, stream>>>(partials, out_loss, out_commit);
}